// Round 10
// baseline (522.425 us; speedup 1.0000x reference)
//
#include <hip/hip_runtime.h>

// TS2Vec hierarchical contrastive loss — bf16 MFMA, pipelined fixed-bias LSE.
//
// Pyramid [16][L][C] bf16 per depth (raw values).
//
// temp: row loss = LSE_{c!=r}(S[r,c]) - S[r,partner], S = Z Z^T, M=2L rows.
//
// R17/R18: SYMMETRIC-TRIANGLE for d0 (75% of tile work). d0 = 4224 blocks,
// one per (b, RB<=CB) 128x128 tile-pair; 16896 tiles vs 32768 (0.516x).
// Off-diag blocks feed BOTH directions: row-dir (rows RB, fixed-bias LSE) and
// col-dir (rows CB: per-tile column LSE via 8-value local reduce +
// shfl_xor(16,32), LDS scratch, cross-wave combine after the tile barrier).
//
// R18 post-mortem of R17's NaN: logic re-verified line-by-line (coverage,
// col-dir math, positives x2, scratch parity) — clean. Prime suspect: ent
// grew 1.44->8.78 MB -> ws 43.4->50.7 MB, likely past ws_size -> pyr tail
// (d8-d11) OOB -> garbage bf16 (NaN) -> st += NaN. Fix: keep OLD ent layout
// exactly (d0 = 4 chunk-slots/row, ws unchanged = known-safe); combine the 8
// block-partials per (row,chunk) with a 64-bit CAS LSE-merge ((m,s) packed
// u64; commutative; FNEG-init annihilates). d0 ent region initialized by
// transpose kernel. Also reverted the untested gload imm-offset staging to
// the known-good 5-pointer form. d>=1 path unchanged (direct stores).
//
// Scheduling ledger (R9-R16): ILP hoist, forced occupancy (spills at <128
// VGPR), counted vmcnt depth, launch fusion, barrier-free (-2.4x),
// anti-phase+setprio — all neutral or worse; ~200µs temp plateau, all pipes
// <35%. Work reduction is the remaining lever.
//
// exp/log base-2 via __builtin_amdgcn_{exp2f,logf}. NOTE: never __exp2f/
// __log2f (glibc math.h reserved-name collision under hipcc g++ driver).

#define B_DIM 8
#define C_DIM 320
#define T_DIM 2048
#define NDEPTH 12
#define LOG2E 1.44269504088896340736f
#define LN2 0.69314718055994530942f
#define FNEG (-3.0e38f)
#define NBLK_D0 4224
#define NBLK_TEMP 4648
#define NBLK_INST 256

typedef __attribute__((ext_vector_type(8))) short bf16x8;
typedef __attribute__((ext_vector_type(4))) float f32x4;

#define AS1 __attribute__((address_space(1)))
#define AS3 __attribute__((address_space(3)))

__device__ inline void gload_lds16(const void* g, void* l) {
  __builtin_amdgcn_global_load_lds((const AS1 unsigned int*)g, (AS3 unsigned int*)l,
                                   16, 0, 0);
}

__device__ inline float fast_exp2(float x) { return __builtin_amdgcn_exp2f(x); }
__device__ inline float fast_log2(float x) { return __builtin_amdgcn_logf(x); }

__device__ inline float bf2f(unsigned short s) {
  unsigned u = ((unsigned)s) << 16;
  return __builtin_bit_cast(float, u);
}
__device__ inline unsigned short f2bf(float f) {
  unsigned u = __builtin_bit_cast(unsigned, f);
  u = (u + 0x7FFFu + ((u >> 16) & 1u)) >> 16;  // round-nearest-even
  return (unsigned short)u;
}

__device__ inline bf16x8 vmax8(bf16x8 a, bf16x8 b) {
  bf16x8 o;
#pragma unroll
  for (int k = 0; k < 8; ++k) {
    unsigned short ua = (unsigned short)a[k], ub = (unsigned short)b[k];
    o[k] = (short)(bf2f(ua) > bf2f(ub) ? ua : ub);
  }
  return o;
}

// 64-bit CAS LSE-merge: slot packs (m in lo32, s in hi32). Commutative and
// associative; slots start at (FNEG, 0) -> exp2(-inf)=0 annihilates init.
__device__ inline void casLSE(unsigned long long* p, float m, float s) {
  unsigned long long cur = *(volatile unsigned long long*)p, assumed;
  do {
    assumed = cur;
    float m0 = __builtin_bit_cast(float, (unsigned)(assumed & 0xFFFFFFFFull));
    float s0 = __builtin_bit_cast(float, (unsigned)(assumed >> 32));
    float mn = fmaxf(m0, m);
    float sn = s0 * fast_exp2((m0 - mn) * LOG2E) + s * fast_exp2((m - mn) * LOG2E);
    unsigned long long nv =
        ((unsigned long long)__builtin_bit_cast(unsigned, sn) << 32) |
        (unsigned long long)__builtin_bit_cast(unsigned, mn);
    cur = atomicCAS(p, assumed, nv);
  } while (cur != assumed);
}

// ------- transpose+convert: [B][C][T]f32 -> [16][T][C]bf16 (raw) ----------
// Fused: zeroes acc/ticket (block 0) and inits the d0 ent region (131072
// u64 slots) to (FNEG, 0) for the CAS LSE-merge.
__global__ __launch_bounds__(256) void transpose_kernel(const float* __restrict__ z1,
                                                        const float* __restrict__ z2,
                                                        unsigned short* __restrict__ out,
                                                        float* __restrict__ acc,
                                                        float2* __restrict__ ent) {
  __shared__ float tile[32][33];
  if (blockIdx.x == 0 && blockIdx.y == 0 && blockIdx.z == 0 &&
      threadIdx.x == 0 && threadIdx.y == 0) {
    acc[0] = 0.0f;
    acc[1] = 0.0f;
    ((unsigned*)acc)[2] = 0u;  // merge finalize ticket
  }
  {
    int gid = ((blockIdx.z * gridDim.y + blockIdx.y) * gridDim.x + blockIdx.x) * 256 +
              threadIdx.y * 32 + threadIdx.x;
    if (gid < 131072) {
      unsigned long long init =
          (unsigned long long)__builtin_bit_cast(unsigned, FNEG);  // m=FNEG, s=0
      ((unsigned long long*)ent)[gid] = init;
    }
  }
  const int zi = blockIdx.z >> 3;
  const int b = blockIdx.z & 7;
  const float* in = zi ? z2 : z1;
  const int t0 = blockIdx.x * 32;
  const int c0 = blockIdx.y * 32;
  const int tx = threadIdx.x;
  const int ty = threadIdx.y;
#pragma unroll
  for (int k = 0; k < 4; ++k) {
    int c = c0 + ty + k * 8;
    tile[ty + k * 8][tx] = in[((size_t)b * C_DIM + c) * T_DIM + t0 + tx];
  }
  __syncthreads();
#pragma unroll
  for (int k = 0; k < 4; ++k) {
    int t = t0 + ty + k * 8;
    out[((size_t)(zi * B_DIM + b) * T_DIM + t) * C_DIM + c0 + tx] = f2bf(tile[tx][ty + k * 8]);
  }
}

// ---------------- all 11 pool levels in ONE kernel ------------------------
__global__ __launch_bounds__(256) void pool_all_kernel(unsigned short* __restrict__ pyr) {
  constexpr size_t ZOFF[NDEPTH] = {0,        10485760, 15728640, 18350080,
                                   19660800, 20316160, 20643840, 20807680,
                                   20889600, 20930560, 20951040, 20961280};
  __shared__ __align__(16) unsigned short A_[32 * 8 * 8];
  __shared__ __align__(16) unsigned short B_[16 * 8 * 8];
  __shared__ __align__(16) unsigned short D8_[8 * 8 * 8];

  const int t = threadIdx.x;
  const int c2 = t & 7, lg = t >> 3;
  const int bb = blockIdx.y;
  const int c0 = blockIdx.x * 64 + c2 * 8;

  auto dst = [&](int s, int nL, int l) -> bf16x8* {
    return (bf16x8*)(pyr + ZOFF[s] + ((size_t)(bb * nL + l)) * C_DIM + c0);
  };
  auto lv = [&](unsigned short* base, int i) -> bf16x8* {
    return (bf16x8*)(base + (size_t)(i * 8 + c2) * 8);
  };

  for (int it = 0; it < 8; ++it) {
    bf16x8 v[8];
#pragma unroll
    for (int k = 0; k < 8; ++k)
      v[k] = *(const bf16x8*)(pyr + ZOFF[0] +
                              ((size_t)(bb * 2048 + it * 256 + lg * 8 + k)) * C_DIM + c0);
    bf16x8 m1[4];
#pragma unroll
    for (int j = 0; j < 4; ++j) {
      m1[j] = vmax8(v[2 * j], v[2 * j + 1]);
      *dst(1, 1024, it * 128 + lg * 4 + j) = m1[j];
    }
    bf16x8 m2[2];
#pragma unroll
    for (int j = 0; j < 2; ++j) {
      m2[j] = vmax8(m1[2 * j], m1[2 * j + 1]);
      *dst(2, 512, it * 64 + lg * 2 + j) = m2[j];
    }
    bf16x8 m3 = vmax8(m2[0], m2[1]);
    *dst(3, 256, it * 32 + lg) = m3;
    *lv(A_, lg) = m3;
    __syncthreads();
    if (lg < 16) {
      bf16x8 x = vmax8(*lv(A_, 2 * lg), *lv(A_, 2 * lg + 1));
      *dst(4, 128, it * 16 + lg) = x;
      *lv(B_, lg) = x;
    }
    __syncthreads();
    if (lg < 8) {
      bf16x8 x = vmax8(*lv(B_, 2 * lg), *lv(B_, 2 * lg + 1));
      *dst(5, 64, it * 8 + lg) = x;
      *lv(A_, lg) = x;
    }
    __syncthreads();
    if (lg < 4) {
      bf16x8 x = vmax8(*lv(A_, 2 * lg), *lv(A_, 2 * lg + 1));
      *dst(6, 32, it * 4 + lg) = x;
      *lv(B_, lg) = x;
    }
    __syncthreads();
    if (lg < 2) {
      bf16x8 x = vmax8(*lv(B_, 2 * lg), *lv(B_, 2 * lg + 1));
      *dst(7, 16, it * 2 + lg) = x;
      *lv(A_, lg) = x;
    }
    __syncthreads();
    if (lg == 0) {
      bf16x8 x = vmax8(*lv(A_, 0), *lv(A_, 1));
      *dst(8, 8, it) = x;
      *lv(D8_, it) = x;
    }
    __syncthreads();
  }
  if (lg < 4) {
    bf16x8 x = vmax8(*lv(D8_, 2 * lg), *lv(D8_, 2 * lg + 1));
    *dst(9, 4, lg) = x;
    *lv(A_, lg) = x;
  }
  __syncthreads();
  if (lg < 2) {
    bf16x8 x = vmax8(*lv(A_, 2 * lg), *lv(A_, 2 * lg + 1));
    *dst(10, 2, lg) = x;
    *lv(B_, lg) = x;
  }
  __syncthreads();
  if (lg == 0) {
    bf16x8 x = vmax8(*lv(B_, 0), *lv(B_, 1));
    *dst(11, 1, 0) = x;
  }
}

// ---------------- fused temp + inst loss ----------------------------------
__global__ __launch_bounds__(256, 2) void temp_kernel(const unsigned short* __restrict__ pyr,
                                                      float2* __restrict__ ent,
                                                      float* __restrict__ acc) {
  constexpr int Ls[NDEPTH] = {2048, 1024, 512, 256, 128, 64, 32, 16, 8, 4, 2, 1};
  constexpr int SP[NDEPTH] = {4, 2, 1, 1, 1, 1, 1, 1, 1, 1, 1, 1};
  constexpr int NB[NDEPTH] = {1024, 256, 64, 32, 16, 8, 8, 8, 8, 8, 8, 8};
  constexpr size_t ZOFF[NDEPTH] = {0,        10485760, 15728640, 18350080,
                                   19660800, 20316160, 20643840, 20807680,
                                   20889600, 20930560, 20951040, 20961280};
  constexpr size_t EBASE[NDEPTH] = {0,      131072, 163840, 172032, 176128, 178176,
                                    179200, 179712, 179968, 180096, 180160, 180192};
  constexpr float SCL[NDEPTH] = {
      1.f / (16 * 2048.f), 1.f / (16 * 1024.f), 1.f / (16 * 512.f), 1.f / (16 * 256.f),
      1.f / (16 * 128.f),  1.f / (16 * 64.f),   1.f / (16 * 32.f),  1.f / (16 * 16.f),
      1.f / (16 * 8.f),    1.f / (16 * 4.f),    1.f / (16 * 2.f),   1.f / (16 * 1.f)};

  __shared__ __align__(16) unsigned short Bs[3 * 10240];  // 61440 B, 3 bufs
  __shared__ float2 colscr[2][4][2][16];                  // 2048 B col scratch

  const int tid = threadIdx.x;
  const int w = tid >> 6, lane = tid & 63;
  const int lr = lane & 15, lg = lane >> 4;

  // ================= inst path (blocks >= NBLK_TEMP) =================
  if (blockIdx.x >= NBLK_TEMP) {
    const int gw = (blockIdx.x - NBLK_TEMP) * 4 + w;
    const int nw = NBLK_INST * 4;
    float partial = 0.f;
    for (int gl = gw; gl < 4095; gl += nw) {
      int d = 0, l = gl;
      while (l >= Ls[d]) { l -= Ls[d]; ++d; }
      const int L = Ls[d];
      const unsigned short* Z = pyr + ZOFF[d];
      const unsigned short* rp = Z + ((size_t)lr * L + l) * C_DIM + lg * 8;
      bf16x8 fr[10];
#pragma unroll
      for (int ks = 0; ks < 10; ++ks) fr[ks] = *(const bf16x8*)(rp + ks * 32);
      f32x4 c4 = (f32x4){0.f, 0.f, 0.f, 0.f};
#pragma unroll
      for (int ks = 0; ks < 10; ++ks)
        c4 = __builtin_amdgcn_mfma_f32_16x16x32_bf16(fr[ks], fr[ks], c4, 0, 0, 0);
#pragma unroll
      for (int rg = 0; rg < 4; ++rg) {
        int gr = lg * 4 + rg, gc = lr;
        float v = c4[rg];
        int prt = (gr + 8) & 15;
        float ps = (gc == prt) ? v : 0.f;
        float x = (gc != gr) ? v * LOG2E : FNEG;
        float mx = x;
#pragma unroll
        for (int k = 1; k < 16; k <<= 1) mx = fmaxf(mx, __shfl_xor(mx, k));
        float se = fast_exp2(fmaxf(x - mx, -128.f));
#pragma unroll
        for (int k = 1; k < 16; k <<= 1) {
          se += __shfl_xor(se, k);
          ps += __shfl_xor(ps, k);
        }
        if (lr == 0) partial += ((mx + fast_log2(se)) * LN2 - ps) * SCL[d];
      }
    }
#pragma unroll
    for (int k = 1; k < 64; k <<= 1) partial += __shfl_xor(partial, k);
    if (lane == 0) atomicAdd(acc, partial);
    return;
  }

  // ================= temp path =================
  int bid = blockIdx.x;
  bool sym;
  int d, b, r0, cbase, ntiles, entStride, entSlot, RB = 0, CB = 0;
  if (bid < NBLK_D0) {
    // d0 symmetric tile-pair (RB <= CB), 128x128 per block, 4 col-tiles
    sym = true;
    d = 0;
    b = bid & 7;
    int t2 = bid >> 3;  // 0..527 triangular index
    int rb = 0;
    while (t2 >= 32 - rb) { t2 -= 32 - rb; ++rb; }
    RB = rb;
    CB = rb + t2;
    r0 = RB * 128;
    cbase = CB * 128;
    ntiles = 4;
    entStride = 4;        // old chunk layout
    entSlot = CB >> 3;    // row-dir chunk
  } else {
    sym = false;
    int b2 = bid - NBLK_D0;
    d = 1;
    while (b2 >= NB[d]) { b2 -= NB[d]; ++d; }
    b = b2 & 7;
    int t2 = b2 >> 3;
    const int spd = SP[d];
    entSlot = t2 % spd;
    int rb = t2 / spd;
    r0 = rb * 128;
    const int csz = (2 * Ls[d]) / spd;
    cbase = entSlot * csz;
    ntiles = (csz + 31) >> 5;
    entStride = spd;
  }
  const int L = Ls[d], M = 2 * L;
  const float scale = SCL[d];
  const bool doCol = sym && (RB != CB);
  const unsigned short* Z = pyr + ZOFF[d];

  auto rowptr = [&](int r) -> const unsigned short* {
    r = (r < M) ? r : (M - 1);
    int idx = (r < L) ? (b * L + r) : ((B_DIM + b) * L + (r - L));
    return Z + (size_t)idx * C_DIM;
  };

  // A fragments: this wave's 32 rows, whole K (80 regs) — issue early
  const int rwave = r0 + w * 32;
  bf16x8 afrag[2][10];
#pragma unroll
  for (int rs = 0; rs < 2; ++rs) {
    const unsigned short* rp = rowptr(rwave + rs * 16 + lr) + lg * 8;
#pragma unroll
    for (int ks = 0; ks < 10; ++ks) afrag[rs][ks] = *(const bf16x8*)(rp + ks * 32);
  }

  // staging pointers: per-blob, advance 32 cols/tile, +7*L*C at half boundary
  const long stepEl = 32 * (long)C_DIM;
  const long extraEl = (long)7 * L * C_DIM;
  const unsigned short* gp[5];
#pragma unroll
  for (int i = 0; i < 5; ++i) {
    int blob = w * 5 + i, ks = blob >> 1, sub = blob & 1;
    int c = cbase + sub * 16 + lr;
    c = (c < M) ? c : (M - 1);
    long idx = (long)b * L + c + ((c >= L) ? (long)7 * L : 0);
    gp[i] = Z + idx * C_DIM + ks * 32 + lg * 8;
  }
  int c0next = cbase;

  auto stage = [&](int buf) {
#pragma unroll
    for (int i = 0; i < 5; ++i)
      gload_lds16(gp[i], &Bs[buf * 10240 + (w * 5 + i) * 512]);
    long adv = stepEl;
    c0next += 32;
    if (c0next == L) adv += extraEl;
#pragma unroll
    for (int i = 0; i < 5; ++i) gp[i] += adv;
  };

  auto mfmaTile = [&](int buf, f32x4 (&cc)[2][2]) {
#pragma unroll
    for (int rs = 0; rs < 2; ++rs)
#pragma unroll
      for (int cs = 0; cs < 2; ++cs) cc[rs][cs] = (f32x4){0.f, 0.f, 0.f, 0.f};
#pragma unroll
    for (int ks = 0; ks < 10; ++ks) {
      bf16x8 b0 = *(const bf16x8*)&Bs[buf * 10240 + (ks * 2 + 0) * 512 + lane * 8];
      bf16x8 b1 = *(const bf16x8*)&Bs[buf * 10240 + (ks * 2 + 1) * 512 + lane * 8];
#pragma unroll
      for (int rs = 0; rs < 2; ++rs) {
        cc[rs][0] = __builtin_amdgcn_mfma_f32_16x16x32_bf16(afrag[rs][ks], b0, cc[rs][0], 0, 0, 0);
        cc[rs][1] = __builtin_amdgcn_mfma_f32_16x16x32_bf16(afrag[rs][ks], b1, cc[rs][1], 0, 0, 0);
      }
    }
  };

  // wave-uniform slow-tile ranges
  const int rlo = rwave, rhi = rwave + 31;
  int plo = 1, phi = 0;  // empty
  if (d <= 5) {          // L>=64, rwave%32==0 -> rows lie in one half
    plo = (rlo < L) ? rlo + L : rlo - L;
    phi = plo + 31;
  }

  // per-lane per-row state: fixed bias (raw), sum
  float bias[8], s_[8];
  float pacc = 0.f;
#pragma unroll
  for (int i = 0; i < 8; ++i) { bias[i] = FNEG; s_[i] = 0.f; }

  auto epiSlow = [&](f32x4 (&cp)[2][2], int eclo) {
    const int gc0 = eclo + lr, gc1 = gc0 + 16;
#pragma unroll
    for (int rs = 0; rs < 2; ++rs) {
#pragma unroll
      for (int rg = 0; rg < 4; ++rg) {
        int i = rs * 4 + rg;
        int gr = rwave + rs * 16 + lg * 4 + rg;
        int prt = (gr < L) ? (gr + L) : (gr - L);
        float v0 = cp[rs][0][rg], v1 = cp[rs][1][rg];
        if (gr < M) {
          if (gc0 == prt) pacc += v0;
          if (gc1 == prt) pacc += v1;
        }
        float x0 = (gc0 < M && gc0 != gr) ? v0 : FNEG;
        float x1 = (gc1 < M && gc1 != gr) ? v1 : FNEG;
        float mn = fmaxf(bias[i], fmaxf(x0, x1));
        s_[i] = s_[i] * fast_exp2((bias[i] - mn) * LOG2E) +
                fast_exp2((x0 - mn) * LOG2E) + fast_exp2((x1 - mn) * LOG2E);
        bias[i] = mn;
      }
    }
  };

  auto epiFast = [&](f32x4 (&cp)[2][2]) {
    float flag = FNEG;
#pragma unroll
    for (int rs = 0; rs < 2; ++rs) {
#pragma unroll
      for (int rg = 0; rg < 4; ++rg) {
        int i = rs * 4 + rg;
        float bl = bias[i] * LOG2E;
        float f0 = __builtin_fmaf(cp[rs][0][rg], LOG2E, -bl);
        float f1 = __builtin_fmaf(cp[rs][1][rg], LOG2E, -bl);
        cp[rs][0][rg] = f0;
        cp[rs][1][rg] = f1;
        flag = fmaxf(flag, fmaxf(f0, f1));
      }
    }
    if (__any(flag > 60.f)) {  // rare: raise bias online
#pragma unroll
      for (int rs = 0; rs < 2; ++rs) {
#pragma unroll
        for (int rg = 0; rg < 4; ++rg) {
          int i = rs * 4 + rg;
          float bl = bias[i] * LOG2E;
          float v0 = (cp[rs][0][rg] + bl) * LN2;
          float v1 = (cp[rs][1][rg] + bl) * LN2;
          float mn = fmaxf(bias[i], fmaxf(v0, v1));
          s_[i] = s_[i] * fast_exp2((bias[i] - mn) * LOG2E) +
                  fast_exp2((v0 - mn) * LOG2E) + fast_exp2((v1 - mn) * LOG2E);
          bias[i] = mn;
        }
      }
    } else {
#pragma unroll
      for (int rs = 0; rs < 2; ++rs)
#pragma unroll
        for (int rg = 0; rg < 4; ++rg)
          s_[rs * 4 + rg] += fast_exp2(cp[rs][0][rg]) + fast_exp2(cp[rs][1][rg]);
    }
  };

  auto epi = [&](f32x4 (&cp)[2][2], int et) {
    const int eclo = cbase + et * 32, echi = eclo + 31;
    bool slowT = (et == 0) || (d >= 6) ||
                 (echi >= rlo && eclo <= rhi) ||   // diagonal in tile
                 (echi >= plo && eclo <= phi);     // partner col in tile
    if (slowT) epiSlow(cp, eclo); else epiFast(cp);
  };

  // column-direction per-tile LSE (sym off-diag only): per lane 8 values of
  // col gc over this wave's 32 rows -> local reduce -> shfl over lg -> LDS.
  auto colEpi = [&](f32x4 (&cp)[2][2], int et) {
#pragma unroll
    for (int cs = 0; cs < 2; ++cs) {
      float m = cp[0][cs][0];
#pragma unroll
      for (int rg = 1; rg < 4; ++rg) m = fmaxf(m, cp[0][cs][rg]);
#pragma unroll
      for (int rg = 0; rg < 4; ++rg) m = fmaxf(m, cp[1][cs][rg]);
      float s = 0.f;
#pragma unroll
      for (int rg = 0; rg < 4; ++rg)
        s += fast_exp2((cp[0][cs][rg] - m) * LOG2E) +
             fast_exp2((cp[1][cs][rg] - m) * LOG2E);
#pragma unroll
      for (int k = 16; k <= 32; k <<= 1) {
        float m2 = __shfl_xor(m, k), s2 = __shfl_xor(s, k);
        float mn = fmaxf(m, m2);
        s = s * fast_exp2((m - mn) * LOG2E) + s2 * fast_exp2((m2 - mn) * LOG2E);
        m = mn;
      }
      if (lg == 0) colscr[et & 1][w][cs][lr] = make_float2(m, s);
    }
  };

  // cross-wave combine of tile et's col partials (after a barrier) ->
  // CAS-merge into ent[(b*M+gcol)*4 + RB>>3] (old chunk layout).
  auto colCombine = [&](int et) {
    if (lane < 8) {
      int c = w * 8 + lane;  // col within tile, 0..31
      int cs = c >> 4, lr2 = c & 15;
      float2 e0 = colscr[et & 1][0][cs][lr2];
      float2 e1 = colscr[et & 1][1][cs][lr2];
      float2 e2 = colscr[et & 1][2][cs][lr2];
      float2 e3 = colscr[et & 1][3][cs][lr2];
      float m = fmaxf(fmaxf(e0.x, e1.x), fmaxf(e2.x, e3.x));
      float s = e0.y * fast_exp2((e0.x - m) * LOG2E) +
                e1.y * fast_exp2((e1.x - m) * LOG2E) +
                e2.y * fast_exp2((e2.x - m) * LOG2E) +
                e3.y * fast_exp2((e3.x - m) * LOG2E);
      int gcol = cbase + et * 32 + c;
      casLSE((unsigned long long*)&ent[((size_t)(b * M + gcol)) * 4 + (RB >> 3)], m, s);
    }
  };

  // ---- main loop: triple-buffered, counted vmcnt, raw barriers ----
  f32x4 cA[2][2];
  stage(0);
  if (ntiles > 1) {
    stage(1);
    asm volatile("s_waitcnt vmcnt(5)" ::: "memory");  // afrag + tile0 done
  } else {
    asm volatile("s_waitcnt vmcnt(0)" ::: "memory");
  }
  __builtin_amdgcn_s_barrier();
  int bufC = 0, bufS = 2;
  for (int ct = 0; ct < ntiles; ++ct) {
    if (ct + 2 < ntiles) stage(bufS);
    if (doCol && ct > 0) colCombine(ct - 1);
    mfmaTile(bufC, cA);
    if (doCol) colEpi(cA, ct);  // before epi (epiFast clobbers cA)
    epi(cA, ct);
    if (ct + 1 < ntiles) {
      if (ct + 2 < ntiles) {
        asm volatile("s_waitcnt vmcnt(5)" ::: "memory");
      } else {
        asm volatile("s_waitcnt vmcnt(0)" ::: "memory");
      }
      __builtin_amdgcn_s_barrier();
    }
    bufC = (bufC == 2) ? 0 : bufC + 1;
    bufS = (bufS == 2) ? 0 : bufS + 1;
  }
  if (doCol) {  // block-uniform: barrier then combine final tile's cols
    __syncthreads();
    colCombine(ntiles - 1);
  }

  // merge (bias,s) across the 16 lr-lanes per row, write/merge row partial
#pragma unroll
  for (int rs = 0; rs < 2; ++rs) {
#pragma unroll
    for (int rg = 0; rg < 4; ++rg) {
      int i = rs * 4 + rg;
      float m = bias[i], s = s_[i];
      float mt = m;
#pragma unroll
      for (int k = 1; k < 16; k <<= 1) mt = fmaxf(mt, __shfl_xor(mt, k));
      float st = s * fast_exp2((m - mt) * LOG2E);  // bias=FNEG lanes -> 0
#pragma unroll
      for (int k = 1; k < 16; k <<= 1) st += __shfl_xor(st, k);
      int gr = rwave + rs * 16 + lg * 4 + rg;
      if (gr < M && lr == 0) {
        if (sym) {
          casLSE((unsigned long long*)&ent[((size_t)(b * M + gr)) * 4 + entSlot], mt, st);
        } else {
          ent[EBASE[d] + ((size_t)(b * M + gr)) * entStride + entSlot] = make_float2(mt, st);
        }
      }
    }
  }

  // positives: one atomic per wave; sym counts each unordered pair once -> x2
#pragma unroll
  for (int k = 1; k < 64; k <<= 1) pacc += __shfl_xor(pacc, k);
  if (lane == 0) atomicAdd(acc + 1, -pacc * scale * (sym ? 2.0f : 1.0f));
}

// ------- merge column-chunk partials -> temp loss (+ fused finalize) ------
__global__ __launch_bounds__(256) void merge_kernel(const float2* __restrict__ ent,
                                                    float* __restrict__ acc,
                                                    float* __restrict__ out) {
  constexpr int Ls[NDEPTH] = {2048, 1024, 512, 256, 128, 64, 32, 16, 8, 4, 2, 1};
  constexpr int SP[NDEPTH] = {4, 2, 1, 1, 1, 1, 1, 1, 1, 1, 1, 1};
  constexpr size_t EBASE[NDEPTH] = {0,      131072, 163840, 172032, 176128, 178176,
                                    179200, 179712, 179968, 180096, 180160, 180192};
  constexpr int RBASE[NDEPTH] = {0,     32768, 49152, 57344, 61440, 63488,
                                 64512, 65024, 65280, 65408, 65472, 65504};
  __shared__ float red[4];
  int i = blockIdx.x * 256 + threadIdx.x;
  float partial = 0.f;
  if (i < 65520) {
    int d = 0;
    while (d < 11 && i >= RBASE[d + 1]) ++d;
    int rem = i - RBASE[d];
    int sp = SP[d];
    const float2* e = ent + EBASE[d] + (size_t)rem * sp;
    float mt = FNEG;
    for (int c = 0; c < sp; ++c) mt = fmaxf(mt, e[c].x);
    float st = 0.f;
    for (int c = 0; c < sp; ++c) st += e[c].y * fast_exp2((e[c].x - mt) * LOG2E);
    partial = (mt + LN2 * fast_log2(st)) / (16.f * (float)Ls[d]);
  }
#pragma unroll
  for (int k = 1; k < 64; k <<= 1) partial += __shfl_xor(partial, k);
  if ((threadIdx.x & 63) == 0) red[threadIdx.x >> 6] = partial;
  __syncthreads();
  if (threadIdx.x == 0) {
    atomicAdd(acc + 1, red[0] + red[1] + red[2] + red[3]);
    __threadfence();
    unsigned tk = atomicAdd((unsigned*)(acc + 2), 1u);
    if (tk == gridDim.x - 1) {  // last merge block: finalize
      float inst = atomicAdd(acc + 0, 0.0f) * (1.0f / 11.0f);
      float temp = atomicAdd(acc + 1, 0.0f) * (1.0f / 11.0f);
      out[0] = 0.5f * inst + 0.5f * temp;  // ALPHA = 0.5
      out[1] = inst;
      out[2] = temp;
    }
  }
}

// ---------------- launch ----------------
extern "C" void kernel_launch(void* const* d_in, const int* in_sizes, int n_in,
                              void* d_out, int out_size, void* d_ws, size_t ws_size,
                              hipStream_t stream) {
  const float* z1 = (const float*)d_in[0];
  const float* z2 = (const float*)d_in[1];
  float* out = (float*)d_out;
  float* acc = (float*)d_ws;                   // [0]=inst, [1]=temp, [2]=ticket
  float2* ent = (float2*)((char*)d_ws + 256);  // 180208 used, pad to 180224
  unsigned short* pyr = (unsigned short*)((char*)d_ws + 256 + (size_t)180224 * 8);

  transpose_kernel<<<dim3(T_DIM / 32, C_DIM / 32, 16), dim3(32, 8), 0, stream>>>(z1, z2, pyr, acc, ent);
  pool_all_kernel<<<dim3(C_DIM / 64, 16), 256, 0, stream>>>(pyr);
  temp_kernel<<<dim3(NBLK_TEMP + NBLK_INST), 256, 0, stream>>>(pyr, ent, acc);
  merge_kernel<<<dim3(256), 256, 0, stream>>>(ent, acc, out);
}

// Round 11
// 290.571 us; speedup vs baseline: 1.7979x; 1.7979x over previous
//
#include <hip/hip_runtime.h>

// TS2Vec hierarchical contrastive loss — bf16 MFMA, pipelined fixed-bias LSE.
// FINAL (R19): revert to the verified-best R13 structure (286.06 µs, Round 5).
//
// Pyramid [16][L][C] bf16 per depth (raw values; Gram scales by the SQUARE of
// any operand pre-scale, so no log2e folding).
//
// temp: row loss = LSE_{c!=r}(S[r,c]) - S[r,partner], S = Z Z^T, M=2L rows.
// Fused launch: blocks [0,1448) temp (depth0 col-split x4, depth1 x2),
// blocks [1448,1704) inst. Block = 4 waves x 32 rows; A (whole K=320) in 80
// regs/wave; 32-col B tiles staged via global_load_lds (fragment-ordered 1KB
// blobs, conflict-free ds_read_b128), TRIPLE-buffered with counted vmcnt
// (vmcnt(5) waits only tile t+1's loads; t+2's cross the barrier).
//
// Complete experiment ledger (all measured on MI355X):
//   R9  reg-hoist ILP            -> neutral (compiler pinned at 128 VGPR)
//   R10 forced 3 blk/CU          -> 84 VGPR, spills, +17% (VGPR wall < afrag)
//   R11 triple-buf counted vmcnt -> -2% (kept; prefetch depth was covered)
//   R12 64-row waves (160 VGPR)  -> spills at 128 cap, +79%
//   R13 13->4 launch fusion      -> neutral (kept; gaps were not the cost)
//   R14 barrier-free per-wave    -> +136% (latency-bound, epi x2)
//   R15 anti-phase + setprio     -> neutral (+2%) — convoy theory dead
//   R17 symmetric-triangle (v1)  -> NaN (untested imm-offset staging / ws)
//   R18 symmetric-triangle (CAS) -> passes but +110%: unexplained 2x stall,
//       WRITE_SIZE 1.6->78 MB, FETCH > working set; pipe WORK matched model
//       (MFMA 0.64x, VALU +27%) but stall tripled. Reverted.
// Conclusion: ~200µs temp is a STRUCTURE plateau (128-VGPR wall -> 2
// phase-locked waves/SIMD; all pipes <35%), not a hardware roofline.
//
// Epilogue: fixed per-lane-row bias (init at always-slow tile 0), fast tile =
// fma + exp2 + add per entry; __any(f>60) rescue re-raises bias (exact:
// merge kernel rescales (m,s); lanes stuck at bias=FNEG are annihilated by
// exp2(FNEG-mt)=0 in the merge).
//
// exp/log base-2 via __builtin_amdgcn_{exp2f,logf}. NOTE: never __exp2f/
// __log2f (glibc math.h reserved-name collision under hipcc g++ driver).

#define B_DIM 8
#define C_DIM 320
#define T_DIM 2048
#define NDEPTH 12
#define LOG2E 1.44269504088896340736f
#define LN2 0.69314718055994530942f
#define FNEG (-3.0e38f)
#define NBLK_TEMP 1448
#define NBLK_INST 256

typedef __attribute__((ext_vector_type(8))) short bf16x8;
typedef __attribute__((ext_vector_type(4))) float f32x4;

#define AS1 __attribute__((address_space(1)))
#define AS3 __attribute__((address_space(3)))

__device__ inline void gload_lds16(const void* g, void* l) {
  __builtin_amdgcn_global_load_lds((const AS1 unsigned int*)g, (AS3 unsigned int*)l,
                                   16, 0, 0);
}

__device__ inline float fast_exp2(float x) { return __builtin_amdgcn_exp2f(x); }
__device__ inline float fast_log2(float x) { return __builtin_amdgcn_logf(x); }

__device__ inline float bf2f(unsigned short s) {
  unsigned u = ((unsigned)s) << 16;
  return __builtin_bit_cast(float, u);
}
__device__ inline unsigned short f2bf(float f) {
  unsigned u = __builtin_bit_cast(unsigned, f);
  u = (u + 0x7FFFu + ((u >> 16) & 1u)) >> 16;  // round-nearest-even
  return (unsigned short)u;
}

__device__ inline bf16x8 vmax8(bf16x8 a, bf16x8 b) {
  bf16x8 o;
#pragma unroll
  for (int k = 0; k < 8; ++k) {
    unsigned short ua = (unsigned short)a[k], ub = (unsigned short)b[k];
    o[k] = (short)(bf2f(ua) > bf2f(ub) ? ua : ub);
  }
  return o;
}

// ------- transpose+convert: [B][C][T]f32 -> [16][T][C]bf16 (raw) ----------
// Fused: block (0,0,0) also zeroes acc[0..1] and the merge ticket counter.
__global__ __launch_bounds__(256) void transpose_kernel(const float* __restrict__ z1,
                                                        const float* __restrict__ z2,
                                                        unsigned short* __restrict__ out,
                                                        float* __restrict__ acc) {
  __shared__ float tile[32][33];
  if (blockIdx.x == 0 && blockIdx.y == 0 && blockIdx.z == 0 &&
      threadIdx.x == 0 && threadIdx.y == 0) {
    acc[0] = 0.0f;
    acc[1] = 0.0f;
    ((unsigned*)acc)[2] = 0u;  // merge finalize ticket
  }
  const int zi = blockIdx.z >> 3;
  const int b = blockIdx.z & 7;
  const float* in = zi ? z2 : z1;
  const int t0 = blockIdx.x * 32;
  const int c0 = blockIdx.y * 32;
  const int tx = threadIdx.x;
  const int ty = threadIdx.y;
#pragma unroll
  for (int k = 0; k < 4; ++k) {
    int c = c0 + ty + k * 8;
    tile[ty + k * 8][tx] = in[((size_t)b * C_DIM + c) * T_DIM + t0 + tx];
  }
  __syncthreads();
#pragma unroll
  for (int k = 0; k < 4; ++k) {
    int t = t0 + ty + k * 8;
    out[((size_t)(zi * B_DIM + b) * T_DIM + t) * C_DIM + c0 + tx] = f2bf(tile[tx][ty + k * 8]);
  }
}

// ---------------- all 11 pool levels in ONE kernel ------------------------
__global__ __launch_bounds__(256) void pool_all_kernel(unsigned short* __restrict__ pyr) {
  constexpr size_t ZOFF[NDEPTH] = {0,        10485760, 15728640, 18350080,
                                   19660800, 20316160, 20643840, 20807680,
                                   20889600, 20930560, 20951040, 20961280};
  __shared__ __align__(16) unsigned short A_[32 * 8 * 8];
  __shared__ __align__(16) unsigned short B_[16 * 8 * 8];
  __shared__ __align__(16) unsigned short D8_[8 * 8 * 8];

  const int t = threadIdx.x;
  const int c2 = t & 7, lg = t >> 3;
  const int bb = blockIdx.y;
  const int c0 = blockIdx.x * 64 + c2 * 8;

  auto dst = [&](int s, int nL, int l) -> bf16x8* {
    return (bf16x8*)(pyr + ZOFF[s] + ((size_t)(bb * nL + l)) * C_DIM + c0);
  };
  auto lv = [&](unsigned short* base, int i) -> bf16x8* {
    return (bf16x8*)(base + (size_t)(i * 8 + c2) * 8);
  };

  for (int it = 0; it < 8; ++it) {
    bf16x8 v[8];
#pragma unroll
    for (int k = 0; k < 8; ++k)
      v[k] = *(const bf16x8*)(pyr + ZOFF[0] +
                              ((size_t)(bb * 2048 + it * 256 + lg * 8 + k)) * C_DIM + c0);
    bf16x8 m1[4];
#pragma unroll
    for (int j = 0; j < 4; ++j) {
      m1[j] = vmax8(v[2 * j], v[2 * j + 1]);
      *dst(1, 1024, it * 128 + lg * 4 + j) = m1[j];
    }
    bf16x8 m2[2];
#pragma unroll
    for (int j = 0; j < 2; ++j) {
      m2[j] = vmax8(m1[2 * j], m1[2 * j + 1]);
      *dst(2, 512, it * 64 + lg * 2 + j) = m2[j];
    }
    bf16x8 m3 = vmax8(m2[0], m2[1]);
    *dst(3, 256, it * 32 + lg) = m3;
    *lv(A_, lg) = m3;
    __syncthreads();
    if (lg < 16) {
      bf16x8 x = vmax8(*lv(A_, 2 * lg), *lv(A_, 2 * lg + 1));
      *dst(4, 128, it * 16 + lg) = x;
      *lv(B_, lg) = x;
    }
    __syncthreads();
    if (lg < 8) {
      bf16x8 x = vmax8(*lv(B_, 2 * lg), *lv(B_, 2 * lg + 1));
      *dst(5, 64, it * 8 + lg) = x;
      *lv(A_, lg) = x;
    }
    __syncthreads();
    if (lg < 4) {
      bf16x8 x = vmax8(*lv(A_, 2 * lg), *lv(A_, 2 * lg + 1));
      *dst(6, 32, it * 4 + lg) = x;
      *lv(B_, lg) = x;
    }
    __syncthreads();
    if (lg < 2) {
      bf16x8 x = vmax8(*lv(B_, 2 * lg), *lv(B_, 2 * lg + 1));
      *dst(7, 16, it * 2 + lg) = x;
      *lv(A_, lg) = x;
    }
    __syncthreads();
    if (lg == 0) {
      bf16x8 x = vmax8(*lv(A_, 0), *lv(A_, 1));
      *dst(8, 8, it) = x;
      *lv(D8_, it) = x;
    }
    __syncthreads();
  }
  if (lg < 4) {
    bf16x8 x = vmax8(*lv(D8_, 2 * lg), *lv(D8_, 2 * lg + 1));
    *dst(9, 4, lg) = x;
    *lv(A_, lg) = x;
  }
  __syncthreads();
  if (lg < 2) {
    bf16x8 x = vmax8(*lv(A_, 2 * lg), *lv(A_, 2 * lg + 1));
    *dst(10, 2, lg) = x;
    *lv(B_, lg) = x;
  }
  __syncthreads();
  if (lg == 0) {
    bf16x8 x = vmax8(*lv(B_, 0), *lv(B_, 1));
    *dst(11, 1, 0) = x;
  }
}

// ---------------- fused temp + inst loss ----------------------------------
__global__ __launch_bounds__(256, 2) void temp_kernel(const unsigned short* __restrict__ pyr,
                                                      float2* __restrict__ ent,
                                                      float* __restrict__ acc) {
  constexpr int Ls[NDEPTH] = {2048, 1024, 512, 256, 128, 64, 32, 16, 8, 4, 2, 1};
  constexpr int SP[NDEPTH] = {4, 2, 1, 1, 1, 1, 1, 1, 1, 1, 1, 1};
  constexpr int NB[NDEPTH] = {1024, 256, 64, 32, 16, 8, 8, 8, 8, 8, 8, 8};
  constexpr size_t ZOFF[NDEPTH] = {0,        10485760, 15728640, 18350080,
                                   19660800, 20316160, 20643840, 20807680,
                                   20889600, 20930560, 20951040, 20961280};
  constexpr size_t EBASE[NDEPTH] = {0,      131072, 163840, 172032, 176128, 178176,
                                    179200, 179712, 179968, 180096, 180160, 180192};
  constexpr float SCL[NDEPTH] = {
      1.f / (16 * 2048.f), 1.f / (16 * 1024.f), 1.f / (16 * 512.f), 1.f / (16 * 256.f),
      1.f / (16 * 128.f),  1.f / (16 * 64.f),   1.f / (16 * 32.f),  1.f / (16 * 16.f),
      1.f / (16 * 8.f),    1.f / (16 * 4.f),    1.f / (16 * 2.f),   1.f / (16 * 1.f)};

  __shared__ __align__(16) unsigned short Bs[3 * 10240];  // 61440 B, 3 bufs

  const int tid = threadIdx.x;
  const int w = tid >> 6, lane = tid & 63;
  const int lr = lane & 15, lg = lane >> 4;

  // ================= inst path (blocks >= NBLK_TEMP) =================
  if (blockIdx.x >= NBLK_TEMP) {
    const int gw = (blockIdx.x - NBLK_TEMP) * 4 + w;
    const int nw = NBLK_INST * 4;
    float partial = 0.f;
    for (int gl = gw; gl < 4095; gl += nw) {
      int d = 0, l = gl;
      while (l >= Ls[d]) { l -= Ls[d]; ++d; }
      const int L = Ls[d];
      const unsigned short* Z = pyr + ZOFF[d];
      const unsigned short* rp = Z + ((size_t)lr * L + l) * C_DIM + lg * 8;
      bf16x8 fr[10];
#pragma unroll
      for (int ks = 0; ks < 10; ++ks) fr[ks] = *(const bf16x8*)(rp + ks * 32);
      f32x4 c4 = (f32x4){0.f, 0.f, 0.f, 0.f};
#pragma unroll
      for (int ks = 0; ks < 10; ++ks)
        c4 = __builtin_amdgcn_mfma_f32_16x16x32_bf16(fr[ks], fr[ks], c4, 0, 0, 0);
#pragma unroll
      for (int rg = 0; rg < 4; ++rg) {
        int gr = lg * 4 + rg, gc = lr;
        float v = c4[rg];
        int prt = (gr + 8) & 15;
        float ps = (gc == prt) ? v : 0.f;
        float x = (gc != gr) ? v * LOG2E : FNEG;
        float mx = x;
#pragma unroll
        for (int k = 1; k < 16; k <<= 1) mx = fmaxf(mx, __shfl_xor(mx, k));
        float se = fast_exp2(fmaxf(x - mx, -128.f));
#pragma unroll
        for (int k = 1; k < 16; k <<= 1) {
          se += __shfl_xor(se, k);
          ps += __shfl_xor(ps, k);
        }
        if (lr == 0) partial += ((mx + fast_log2(se)) * LN2 - ps) * SCL[d];
      }
    }
#pragma unroll
    for (int k = 1; k < 64; k <<= 1) partial += __shfl_xor(partial, k);
    if (lane == 0) atomicAdd(acc, partial);
    return;
  }

  // ================= temp path =================
  int bid = blockIdx.x;
  int d = 0;
  while (bid >= NB[d]) { bid -= NB[d]; ++d; }
  const int L = Ls[d], M = 2 * L, sp = SP[d];
  const int csz = M / sp;
  const int ntiles = (csz + 31) >> 5;
  const int b = bid & 7;  // batch fastest -> XCD L2 affinity
  const int t2 = bid >> 3;
  const int chunk = t2 % sp;
  const int rb = t2 / sp;
  const int r0 = rb * 128;
  const int cbase = chunk * csz;
  const float scale = SCL[d];
  const unsigned short* Z = pyr + ZOFF[d];

  auto rowptr = [&](int r) -> const unsigned short* {
    r = (r < M) ? r : (M - 1);
    int idx = (r < L) ? (b * L + r) : ((B_DIM + b) * L + (r - L));
    return Z + (size_t)idx * C_DIM;
  };

  // A fragments: this wave's 32 rows, whole K (80 regs) — issue early
  const int rwave = r0 + w * 32;
  bf16x8 afrag[2][10];
#pragma unroll
  for (int rs = 0; rs < 2; ++rs) {
    const unsigned short* rp = rowptr(rwave + rs * 16 + lr) + lg * 8;
#pragma unroll
    for (int ks = 0; ks < 10; ++ks) afrag[rs][ks] = *(const bf16x8*)(rp + ks * 32);
  }

  // staging pointers: per-blob, advance 32 cols/tile, +7*L*C at half boundary
  const long stepEl = 32 * (long)C_DIM;
  const long extraEl = (long)7 * L * C_DIM;
  const unsigned short* gp[5];
#pragma unroll
  for (int i = 0; i < 5; ++i) {
    int blob = w * 5 + i, ks = blob >> 1, sub = blob & 1;
    int c = cbase + sub * 16 + lr;
    c = (c < M) ? c : (M - 1);
    long idx = (long)b * L + c + ((c >= L) ? (long)7 * L : 0);
    gp[i] = Z + idx * C_DIM + ks * 32 + lg * 8;
  }
  int c0next = cbase;

  auto stage = [&](int buf) {
#pragma unroll
    for (int i = 0; i < 5; ++i)
      gload_lds16(gp[i], &Bs[buf * 10240 + (w * 5 + i) * 512]);
    long adv = stepEl;
    c0next += 32;
    if (c0next == L) adv += extraEl;
#pragma unroll
    for (int i = 0; i < 5; ++i) gp[i] += adv;
  };

  auto mfmaTile = [&](int buf, f32x4 (&cc)[2][2]) {
#pragma unroll
    for (int rs = 0; rs < 2; ++rs)
#pragma unroll
      for (int cs = 0; cs < 2; ++cs) cc[rs][cs] = (f32x4){0.f, 0.f, 0.f, 0.f};
#pragma unroll
    for (int ks = 0; ks < 10; ++ks) {
      bf16x8 b0 = *(const bf16x8*)&Bs[buf * 10240 + (ks * 2 + 0) * 512 + lane * 8];
      bf16x8 b1 = *(const bf16x8*)&Bs[buf * 10240 + (ks * 2 + 1) * 512 + lane * 8];
#pragma unroll
      for (int rs = 0; rs < 2; ++rs) {
        cc[rs][0] = __builtin_amdgcn_mfma_f32_16x16x32_bf16(afrag[rs][ks], b0, cc[rs][0], 0, 0, 0);
        cc[rs][1] = __builtin_amdgcn_mfma_f32_16x16x32_bf16(afrag[rs][ks], b1, cc[rs][1], 0, 0, 0);
      }
    }
  };

  // wave-uniform slow-tile ranges
  const int rlo = rwave, rhi = rwave + 31;
  int plo = 1, phi = 0;  // empty
  if (d <= 5) {          // L>=64, rwave%32==0 -> rows lie in one half
    plo = (rlo < L) ? rlo + L : rlo - L;
    phi = plo + 31;
  }

  // per-lane per-row state: fixed bias (raw), sum
  float bias[8], s_[8];
  float pacc = 0.f;
#pragma unroll
  for (int i = 0; i < 8; ++i) { bias[i] = FNEG; s_[i] = 0.f; }

  auto epiSlow = [&](f32x4 (&cp)[2][2], int eclo) {
    const int gc0 = eclo + lr, gc1 = gc0 + 16;
#pragma unroll
    for (int rs = 0; rs < 2; ++rs) {
#pragma unroll
      for (int rg = 0; rg < 4; ++rg) {
        int i = rs * 4 + rg;
        int gr = rwave + rs * 16 + lg * 4 + rg;
        int prt = (gr < L) ? (gr + L) : (gr - L);
        float v0 = cp[rs][0][rg], v1 = cp[rs][1][rg];
        if (gr < M) {
          if (gc0 == prt) pacc += v0;
          if (gc1 == prt) pacc += v1;
        }
        float x0 = (gc0 < M && gc0 != gr) ? v0 : FNEG;
        float x1 = (gc1 < M && gc1 != gr) ? v1 : FNEG;
        float mn = fmaxf(bias[i], fmaxf(x0, x1));
        s_[i] = s_[i] * fast_exp2((bias[i] - mn) * LOG2E) +
                fast_exp2((x0 - mn) * LOG2E) + fast_exp2((x1 - mn) * LOG2E);
        bias[i] = mn;
      }
    }
  };

  auto epiFast = [&](f32x4 (&cp)[2][2]) {
    float flag = FNEG;
#pragma unroll
    for (int rs = 0; rs < 2; ++rs) {
#pragma unroll
      for (int rg = 0; rg < 4; ++rg) {
        int i = rs * 4 + rg;
        float bl = bias[i] * LOG2E;
        float f0 = __builtin_fmaf(cp[rs][0][rg], LOG2E, -bl);
        float f1 = __builtin_fmaf(cp[rs][1][rg], LOG2E, -bl);
        cp[rs][0][rg] = f0;
        cp[rs][1][rg] = f1;
        flag = fmaxf(flag, fmaxf(f0, f1));
      }
    }
    if (__any(flag > 60.f)) {  // rare: raise bias online (fast tiles mask-free)
#pragma unroll
      for (int rs = 0; rs < 2; ++rs) {
#pragma unroll
        for (int rg = 0; rg < 4; ++rg) {
          int i = rs * 4 + rg;
          float bl = bias[i] * LOG2E;
          float v0 = (cp[rs][0][rg] + bl) * LN2;
          float v1 = (cp[rs][1][rg] + bl) * LN2;
          float mn = fmaxf(bias[i], fmaxf(v0, v1));
          s_[i] = s_[i] * fast_exp2((bias[i] - mn) * LOG2E) +
                  fast_exp2((v0 - mn) * LOG2E) + fast_exp2((v1 - mn) * LOG2E);
          bias[i] = mn;
        }
      }
    } else {
#pragma unroll
      for (int rs = 0; rs < 2; ++rs)
#pragma unroll
        for (int rg = 0; rg < 4; ++rg)
          s_[rs * 4 + rg] += fast_exp2(cp[rs][0][rg]) + fast_exp2(cp[rs][1][rg]);
    }
  };

  auto epi = [&](f32x4 (&cp)[2][2], int et) {
    const int eclo = cbase + et * 32, echi = eclo + 31;
    bool slowT = (et == 0) || (d >= 6) ||
                 (echi >= rlo && eclo <= rhi) ||   // diagonal in tile
                 (echi >= plo && eclo <= phi);     // partner col in tile
    if (slowT) epiSlow(cp, eclo); else epiFast(cp);
  };

  // ---- main loop: triple-buffered, counted vmcnt, raw barriers ----
  // iter t: stage(t+2) [its buf freed at end of iter t-1], compute tile t,
  // wait OWN t+1 loads (vmcnt(5): t+2's stay in flight across the barrier),
  // s_barrier. VMEM retires in order, so vmcnt(5) == "t+1 done".
  f32x4 cA[2][2];
  stage(0);
  if (ntiles > 1) {
    stage(1);
    asm volatile("s_waitcnt vmcnt(5)" ::: "memory");  // afrag + tile0 done
  } else {
    asm volatile("s_waitcnt vmcnt(0)" ::: "memory");
  }
  __builtin_amdgcn_s_barrier();
  int bufC = 0, bufS = 2;
  for (int ct = 0; ct < ntiles; ++ct) {
    if (ct + 2 < ntiles) stage(bufS);
    mfmaTile(bufC, cA);
    epi(cA, ct);
    if (ct + 1 < ntiles) {
      if (ct + 2 < ntiles) {
        asm volatile("s_waitcnt vmcnt(5)" ::: "memory");  // t+1 done, t+2 in flight
      } else {
        asm volatile("s_waitcnt vmcnt(0)" ::: "memory");  // tail: only t+1 out
      }
      __builtin_amdgcn_s_barrier();
    }
    bufC = (bufC == 2) ? 0 : bufC + 1;
    bufS = (bufS == 2) ? 0 : bufS + 1;
  }

  // merge (bias,s) across the 16 lr-lanes per row, write per-row-chunk partial
#pragma unroll
  for (int rs = 0; rs < 2; ++rs) {
#pragma unroll
    for (int rg = 0; rg < 4; ++rg) {
      int i = rs * 4 + rg;
      float m = bias[i], s = s_[i];
      float mt = m;
#pragma unroll
      for (int k = 1; k < 16; k <<= 1) mt = fmaxf(mt, __shfl_xor(mt, k));
      float st = s * fast_exp2((m - mt) * LOG2E);  // bias=FNEG lanes -> 0
#pragma unroll
      for (int k = 1; k < 16; k <<= 1) st += __shfl_xor(st, k);
      int gr = rwave + rs * 16 + lg * 4 + rg;
      if (gr < M && lr == 0)
        ent[EBASE[d] + ((size_t)(b * M + gr)) * sp + chunk] = make_float2(mt, st);
    }
  }

  // positives (slow tiles only): one atomic per wave
#pragma unroll
  for (int k = 1; k < 64; k <<= 1) pacc += __shfl_xor(pacc, k);
  if (lane == 0) atomicAdd(acc + 1, -pacc * scale);
}

// ------- merge column-chunk partials -> temp loss (+ fused finalize) ------
__global__ __launch_bounds__(256) void merge_kernel(const float2* __restrict__ ent,
                                                    float* __restrict__ acc,
                                                    float* __restrict__ out) {
  constexpr int Ls[NDEPTH] = {2048, 1024, 512, 256, 128, 64, 32, 16, 8, 4, 2, 1};
  constexpr int SP[NDEPTH] = {4, 2, 1, 1, 1, 1, 1, 1, 1, 1, 1, 1};
  constexpr size_t EBASE[NDEPTH] = {0,      131072, 163840, 172032, 176128, 178176,
                                    179200, 179712, 179968, 180096, 180160, 180192};
  constexpr int RBASE[NDEPTH] = {0,     32768, 49152, 57344, 61440, 63488,
                                 64512, 65024, 65280, 65408, 65472, 65504};
  __shared__ float red[4];
  int i = blockIdx.x * 256 + threadIdx.x;
  float partial = 0.f;
  if (i < 65520) {
    int d = 0;
    while (d < 11 && i >= RBASE[d + 1]) ++d;
    int rem = i - RBASE[d];
    int sp = SP[d];
    const float2* e = ent + EBASE[d] + (size_t)rem * sp;
    float mt = FNEG;
    for (int c = 0; c < sp; ++c) mt = fmaxf(mt, e[c].x);
    float st = 0.f;
    for (int c = 0; c < sp; ++c) st += e[c].y * fast_exp2((e[c].x - mt) * LOG2E);
    partial = (mt + LN2 * fast_log2(st)) / (16.f * (float)Ls[d]);
  }
#pragma unroll
  for (int k = 1; k < 64; k <<= 1) partial += __shfl_xor(partial, k);
  if ((threadIdx.x & 63) == 0) red[threadIdx.x >> 6] = partial;
  __syncthreads();
  if (threadIdx.x == 0) {
    atomicAdd(acc + 1, red[0] + red[1] + red[2] + red[3]);
    __threadfence();
    unsigned tk = atomicAdd((unsigned*)(acc + 2), 1u);
    if (tk == gridDim.x - 1) {  // last merge block: finalize
      float inst = atomicAdd(acc + 0, 0.0f) * (1.0f / 11.0f);
      float temp = atomicAdd(acc + 1, 0.0f) * (1.0f / 11.0f);
      out[0] = 0.5f * inst + 0.5f * temp;  // ALPHA = 0.5
      out[1] = inst;
      out[2] = temp;
    }
  }
}

// ---------------- launch ----------------
extern "C" void kernel_launch(void* const* d_in, const int* in_sizes, int n_in,
                              void* d_out, int out_size, void* d_ws, size_t ws_size,
                              hipStream_t stream) {
  const float* z1 = (const float*)d_in[0];
  const float* z2 = (const float*)d_in[1];
  float* out = (float*)d_out;
  float* acc = (float*)d_ws;                   // [0]=inst, [1]=temp, [2]=ticket
  float2* ent = (float2*)((char*)d_ws + 256);  // 180208 used, pad to 180224
  unsigned short* pyr = (unsigned short*)((char*)d_ws + 256 + (size_t)180224 * 8);

  transpose_kernel<<<dim3(T_DIM / 32, C_DIM / 32, 16), dim3(32, 8), 0, stream>>>(z1, z2, pyr, acc);
  pool_all_kernel<<<dim3(C_DIM / 64, 16), 256, 0, stream>>>(pyr);
  temp_kernel<<<dim3(NBLK_TEMP + NBLK_INST), 256, 0, stream>>>(pyr, ent, acc);
  merge_kernel<<<dim3(256), 256, 0, stream>>>(ent, acc, out);
}